// Round 11
// baseline (273.019 us; speedup 1.0000x reference)
//
#include <hip/hip_runtime.h>
#include <hip/hip_bf16.h>

// ---------------------------------------------------------------------------
// 2-layer GCN. g[j] = dinv[j]*(X@W)[j] stored BF16; out[i] = dinv[i]*(g[i]+sum g[j]) + b
// CSR-by-destination built once, reused by both layers.
// R2-R8: bucketed CSR build, bf16 tables, MFMA GEMMs, deep gather unroll.
// R9 FAILED: cooperative fusion (VGPR spill + grid.sync convoy).
// R10: deterministic per-chunk bucket slots (no memset) — but csr_build's
//      per-thread serial chunk walk was latency-bound (90us).
// R11: csr_build flattened+coalesced (idx -> (chunk,slot)), 512 threads/block.
// ---------------------------------------------------------------------------

typedef short bf16x8 __attribute__((ext_vector_type(8)));
typedef float f32x4 __attribute__((ext_vector_type(4)));

#define CHUNK_CAP 112   // per-(bucket,chunk) slot capacity; verified by R10 pass

__device__ __forceinline__ unsigned pack_bf16_2(float a, float b) {
    unsigned ua = __builtin_bit_cast(unsigned, a);
    unsigned ub = __builtin_bit_cast(unsigned, b);
    ua += 0x7FFFu + ((ua >> 16) & 1u);   // RNE to bf16
    ub += 0x7FFFu + ((ub >> 16) & 1u);
    return (ua >> 16) | (ub & 0xFFFF0000u);
}
__device__ __forceinline__ unsigned short bf16_1(float a) {
    unsigned ua = __builtin_bit_cast(unsigned, a);
    ua += 0x7FFFu + ((ua >> 16) & 1u);
    return (unsigned short)(ua >> 16);
}
__device__ __forceinline__ float bf16_lo(unsigned v) {
    return __builtin_bit_cast(float, v << 16);
}
__device__ __forceinline__ float bf16_hi(unsigned v) {
    return __builtin_bit_cast(float, v & 0xFFFF0000u);
}

// partition chunk c (4096 edges) into deterministic per-chunk bucket slots.
// pcnt[b*nchunk+c] fully written every call -> no global init needed.
__global__ __launch_bounds__(256) void partition_det(const int* __restrict__ src,
                                                     const int* __restrict__ dst,
                                                     int* __restrict__ pcnt,
                                                     int2* __restrict__ ebuf,
                                                     int E, int nb, int nchunk) {
    __shared__ int hist[256];
    const int tid = threadIdx.x;
    const int c = blockIdx.x;
    const int c0 = c * 4096;
    for (int t = tid; t < nb; t += 256) hist[t] = 0;
    __syncthreads();
    int s[16], d[16], r[16];
#pragma unroll
    for (int i = 0; i < 16; ++i) {
        int idx = c0 + i * 256 + tid;
        if (idx < E) {
            s[i] = src[idx];
            d[i] = dst[idx];
            r[i] = atomicAdd(&hist[d[i] >> 10], 1);
        } else {
            d[i] = -1;
        }
    }
    __syncthreads();
    for (int t = tid; t < nb; t += 256)
        pcnt[(size_t)t * nchunk + c] = min(hist[t], CHUNK_CAP);
#pragma unroll
    for (int i = 0; i < 16; ++i) {
        if (d[i] >= 0 && r[i] < CHUNK_CAP) {
            int b = d[i] >> 10;
            ebuf[((size_t)b * nchunk + c) * CHUNK_CAP + r[i]] = make_int2(s[i], d[i]);
        }
    }
}

// R11: one 512-thread block per dst-bucket; flattened coalesced slot iteration.
__global__ __launch_bounds__(512) void csr_build_flat(const int2* __restrict__ ebuf,
                                                      const int* __restrict__ pcnt,
                                                      int* __restrict__ offs,
                                                      float* __restrict__ dinv,
                                                      int* __restrict__ csr,
                                                      int N, int E, int nb, int nchunk) {
    __shared__ int hist[1024];
    __shared__ int lofs[1024];
    __shared__ int scnt[1024];
    __shared__ int stmp[512];
    __shared__ int s_e0;
    const int b = blockIdx.x;
    const int tid = threadIdx.x;
    const int n0 = b << 10;

    // own row of per-chunk counts
    for (int c = tid; c < nchunk; c += 512) scnt[c] = pcnt[(size_t)b * nchunk + c];
    // bucket totals -> exclusive base e0 (scan width 256; nb <= 256)
    int tot = 0;
    if (tid < nb) {
        const int* row = pcnt + (size_t)tid * nchunk;
        for (int c = 0; c < nchunk; ++c) tot += row[c];
    }
    if (tid < 256) stmp[tid] = (tid < nb) ? tot : 0;
    __syncthreads();
    int run = (tid < 256) ? stmp[tid] : 0;
    for (int off = 1; off < 256; off <<= 1) {
        int t = (tid >= off && tid < 256) ? stmp[tid - off] : 0;
        __syncthreads();
        if (tid < 256) { run += t; stmp[tid] = run; }
        __syncthreads();
    }
    if (tid == b) s_e0 = run - tot;
    __syncthreads();
    const int e0 = s_e0;
    const int total = nchunk * CHUNK_CAP;
    const int2* ebB = ebuf + (size_t)b * nchunk * CHUNK_CAP;

    // pass A: degree histogram, flat coalesced
    hist[tid] = 0; hist[tid + 512] = 0;
    __syncthreads();
    for (int idx = tid; idx < total; idx += 512) {
        int c = idx / CHUNK_CAP;
        int s2 = idx - c * CHUNK_CAP;
        if (s2 < scnt[c]) atomicAdd(&hist[ebB[idx].y & 1023], 1);
    }
    __syncthreads();
    // block-local exclusive scan of 1024 degrees (2/thread, 512-wide scan)
    const int v0 = hist[tid * 2], v1 = hist[tid * 2 + 1];
    const int tsum = v0 + v1;
    stmp[tid] = tsum;
    __syncthreads();
    run = tsum;
    for (int off = 1; off < 512; off <<= 1) {
        int t = (tid >= off) ? stmp[tid - off] : 0;
        __syncthreads();
        run += t;
        stmp[tid] = run;
        __syncthreads();
    }
    const int s = run - tsum;
    lofs[tid * 2] = s;
    lofs[tid * 2 + 1] = s + v0;
    {
        int node = n0 + tid * 2;
        if (node < N) {
            offs[node] = e0 + s;
            dinv[node] = rsqrtf((float)(v0 + 1));   // +1 self-loop
        }
        if (node + 1 < N) {
            offs[node + 1] = e0 + s + v0;
            dinv[node + 1] = rsqrtf((float)(v1 + 1));
        }
    }
    __syncthreads();
    // pass B: place edges via LDS cursors, flat coalesced
    for (int idx = tid; idx < total; idx += 512) {
        int c = idx / CHUNK_CAP;
        int s2 = idx - c * CHUNK_CAP;
        if (s2 < scnt[c]) {
            int2 p = ebB[idx];
            int pos = atomicAdd(&lofs[p.y & 1023], 1);
            csr[e0 + pos] = p.x;
        }
    }
    if (b == 0 && tid == 0) offs[N] = E;
}

// MFMA GEMM. Gs[r*COUT+c] = bf16( dinv[r] * sum_k X[r,k]*W[k,c] ). K=128.
template <int COUT, bool INBF16>
__global__ __launch_bounds__(256) void gemm_mfma(const void* __restrict__ Xv,
                                                 const float* __restrict__ W,
                                                 const float* __restrict__ dinv,
                                                 unsigned short* __restrict__ Gs, int N) {
    constexpr int BR = 64;
    constexpr int CPT = COUT / 16;
    __shared__ unsigned short sx[BR][136];
    __shared__ unsigned short swT[COUT][136];
    const int tid = threadIdx.x;
    const int r0 = blockIdx.x * BR;

    if constexpr (INBF16) {
        const unsigned* Xb = (const unsigned*)Xv;
#pragma unroll
        for (int q = 0; q < 4; ++q) {
            int off = q * 1024 + tid * 4;
            int row = off >> 6;
            int ku = off & 63;
            size_t grow = (size_t)min(r0 + row, N - 1);
            uint4 v = *reinterpret_cast<const uint4*>(&Xb[grow * 64 + ku]);
            *reinterpret_cast<uint4*>(&sx[row][ku * 2]) = v;
        }
    } else {
        const float* Xf = (const float*)Xv;
#pragma unroll
        for (int q = 0; q < 8; ++q) {
            int off = q * 1024 + tid * 4;
            int row = off >> 7;
            int k = off & 127;
            size_t grow = (size_t)min(r0 + row, N - 1);
            float4 v = *reinterpret_cast<const float4*>(&Xf[grow * 128 + k]);
            uint2 pk;
            pk.x = pack_bf16_2(v.x, v.y);
            pk.y = pack_bf16_2(v.z, v.w);
            *reinterpret_cast<uint2*>(&sx[row][k]) = pk;
        }
    }
#pragma unroll
    for (int q = 0; q < COUT / 8; ++q) {
        int off = q * 1024 + tid * 4;
        int k = off / COUT;
        int c = off % COUT;
        float4 v = *reinterpret_cast<const float4*>(&W[off]);
        swT[c + 0][k] = bf16_1(v.x);
        swT[c + 1][k] = bf16_1(v.y);
        swT[c + 2][k] = bf16_1(v.z);
        swT[c + 3][k] = bf16_1(v.w);
    }
    __syncthreads();

    const int w = tid >> 6;
    const int l = tid & 63;
    const int lr = l & 15;
    const int lkg = l >> 4;
    f32x4 acc[CPT];
#pragma unroll
    for (int c = 0; c < CPT; ++c) acc[c] = f32x4{0.f, 0.f, 0.f, 0.f};

#pragma unroll
    for (int ks = 0; ks < 4; ++ks) {
        const int k0 = ks * 32 + lkg * 8;
        bf16x8 a = *reinterpret_cast<const bf16x8*>(&sx[w * 16 + lr][k0]);
#pragma unroll
        for (int c = 0; c < CPT; ++c) {
            bf16x8 b = *reinterpret_cast<const bf16x8*>(&swT[c * 16 + lr][k0]);
            acc[c] = __builtin_amdgcn_mfma_f32_16x16x32_bf16(a, b, acc[c], 0, 0, 0);
        }
    }

#pragma unroll
    for (int r = 0; r < 4; ++r) {
        int gr = r0 + w * 16 + lkg * 4 + r;
        if (gr < N) {
            float di = dinv[gr];
#pragma unroll
            for (int c = 0; c < CPT; ++c)
                Gs[(size_t)gr * COUT + c * 16 + lr] = bf16_1(acc[c][r] * di);
        }
    }
}

// Layer-1 aggregate: 128 bf16 cols/row, one wave per node, 16-deep gather ladder.
__global__ __launch_bounds__(256) void agg1_kernel(const unsigned* __restrict__ Gb,
                                                   const int* __restrict__ offs,
                                                   const int* __restrict__ csr,
                                                   const float* __restrict__ dinv,
                                                   const float* __restrict__ bias,
                                                   unsigned* __restrict__ outb, int N) {
    int node = (blockIdx.x * blockDim.x + threadIdx.x) >> 6;
    int lane = threadIdx.x & 63;
    if (node >= N) return;
    int e = offs[node];
    const int end = offs[node + 1];
    unsigned sv = Gb[(size_t)node * 64 + lane];
    float ax = bf16_lo(sv), ay = bf16_hi(sv);
    for (; e + 16 <= end; e += 16) {
        int j[16];
#pragma unroll
        for (int q = 0; q < 16; ++q) j[q] = csr[e + q];
        unsigned v[16];
#pragma unroll
        for (int q = 0; q < 16; ++q) v[q] = Gb[(size_t)j[q] * 64 + lane];
#pragma unroll
        for (int q = 0; q < 16; ++q) { ax += bf16_lo(v[q]); ay += bf16_hi(v[q]); }
    }
    for (; e + 8 <= end; e += 8) {
        int j[8];
#pragma unroll
        for (int q = 0; q < 8; ++q) j[q] = csr[e + q];
        unsigned v[8];
#pragma unroll
        for (int q = 0; q < 8; ++q) v[q] = Gb[(size_t)j[q] * 64 + lane];
#pragma unroll
        for (int q = 0; q < 8; ++q) { ax += bf16_lo(v[q]); ay += bf16_hi(v[q]); }
    }
    for (; e + 4 <= end; e += 4) {
        int j0 = csr[e], j1 = csr[e + 1], j2 = csr[e + 2], j3 = csr[e + 3];
        unsigned v0 = Gb[(size_t)j0 * 64 + lane];
        unsigned v1 = Gb[(size_t)j1 * 64 + lane];
        unsigned v2 = Gb[(size_t)j2 * 64 + lane];
        unsigned v3 = Gb[(size_t)j3 * 64 + lane];
        ax += bf16_lo(v0) + bf16_lo(v1) + bf16_lo(v2) + bf16_lo(v3);
        ay += bf16_hi(v0) + bf16_hi(v1) + bf16_hi(v2) + bf16_hi(v3);
    }
    for (; e < end; ++e) {
        unsigned v = Gb[(size_t)csr[e] * 64 + lane];
        ax += bf16_lo(v); ay += bf16_hi(v);
    }
    float di = dinv[node];
    float ox = fmaxf(ax * di + bias[lane * 2 + 0], 0.f);
    float oy = fmaxf(ay * di + bias[lane * 2 + 1], 0.f);
    outb[(size_t)node * 64 + lane] = pack_bf16_2(ox, oy);
}

// Layer-2 aggregate: 64 bf16 cols/row = 32 uints; two nodes per wave; 16-deep ladder.
__global__ __launch_bounds__(256) void agg2_kernel(const unsigned* __restrict__ Gb,
                                                   const int* __restrict__ offs,
                                                   const int* __restrict__ csr,
                                                   const float* __restrict__ dinv,
                                                   const float* __restrict__ bias,
                                                   float* __restrict__ out, int N) {
    int tid = blockIdx.x * blockDim.x + threadIdx.x;
    int node = (tid >> 6) * 2 + ((threadIdx.x >> 5) & 1);
    int c = threadIdx.x & 31;
    if (node >= N) return;
    int e = offs[node];
    const int end = offs[node + 1];
    unsigned sv = Gb[(size_t)node * 32 + c];
    float ax = bf16_lo(sv), ay = bf16_hi(sv);
    for (; e + 16 <= end; e += 16) {
        int j[16];
#pragma unroll
        for (int q = 0; q < 16; ++q) j[q] = csr[e + q];
        unsigned v[16];
#pragma unroll
        for (int q = 0; q < 16; ++q) v[q] = Gb[(size_t)j[q] * 32 + c];
#pragma unroll
        for (int q = 0; q < 16; ++q) { ax += bf16_lo(v[q]); ay += bf16_hi(v[q]); }
    }
    for (; e + 8 <= end; e += 8) {
        int j[8];
#pragma unroll
        for (int q = 0; q < 8; ++q) j[q] = csr[e + q];
        unsigned v[8];
#pragma unroll
        for (int q = 0; q < 8; ++q) v[q] = Gb[(size_t)j[q] * 32 + c];
#pragma unroll
        for (int q = 0; q < 8; ++q) { ax += bf16_lo(v[q]); ay += bf16_hi(v[q]); }
    }
    for (; e + 4 <= end; e += 4) {
        int j0 = csr[e], j1 = csr[e + 1], j2 = csr[e + 2], j3 = csr[e + 3];
        unsigned v0 = Gb[(size_t)j0 * 32 + c];
        unsigned v1 = Gb[(size_t)j1 * 32 + c];
        unsigned v2 = Gb[(size_t)j2 * 32 + c];
        unsigned v3 = Gb[(size_t)j3 * 32 + c];
        ax += bf16_lo(v0) + bf16_lo(v1) + bf16_lo(v2) + bf16_lo(v3);
        ay += bf16_hi(v0) + bf16_hi(v1) + bf16_hi(v2) + bf16_hi(v3);
    }
    for (; e < end; ++e) {
        unsigned v = Gb[(size_t)csr[e] * 32 + c];
        ax += bf16_lo(v); ay += bf16_hi(v);
    }
    float di = dinv[node];
    float2 o;
    o.x = ax * di + bias[c * 2 + 0];
    o.y = ay * di + bias[c * 2 + 1];
    *reinterpret_cast<float2*>(&out[(size_t)node * 64 + c * 2]) = o;
}

extern "C" void kernel_launch(void* const* d_in, const int* in_sizes, int n_in,
                              void* d_out, int out_size, void* d_ws, size_t ws_size,
                              hipStream_t stream) {
    const float* x  = (const float*)d_in[0];
    const int*   ei = (const int*)d_in[1];
    const float* W1 = (const float*)d_in[2];
    const float* b1 = (const float*)d_in[3];
    const float* W2 = (const float*)d_in[4];
    const float* b2 = (const float*)d_in[5];
    float* out = (float*)d_out;

    const int N = in_sizes[0] / 128;
    const int E = in_sizes[1] / 2;
    const int* src = ei;
    const int* dst = ei + E;
    const int nbkt = (N + 1023) >> 10;        // must be <= 256
    const int nchunk = (E + 4095) / 4096;     // must be <= 1024

    // Workspace layout
    unsigned* g1b = (unsigned*)d_ws;                 // N*64 uints (25.6MB); reused as g2b
    unsigned* a1b = g1b + (size_t)N * 64;            // N*64 uints bf16 a1
    unsigned* g2b = g1b;
    int2* ebuf = (int2*)d_ws;                        // nbkt*nchunk*112*8B, aliases g1b+a1b
    char* p = (char*)(a1b + (size_t)N * 64);
    float* dinv = (float*)p; p += (((size_t)N * 4) + 15) & ~(size_t)15;
    int* offs = (int*)p;   p += (((size_t)(N + 1) * 4) + 15) & ~(size_t)15;
    int* csr = (int*)p;    p += (((size_t)E * 4) + 15) & ~(size_t)15;
    int* pcnt = (int*)p;   p += (((size_t)nbkt * nchunk * 4) + 15) & ~(size_t)15;
    if ((size_t)(p - (char*)d_ws) > ws_size || nbkt > 256 || nchunk > 1024 ||
        (size_t)nbkt * nchunk * CHUNK_CAP * 8 > (size_t)N * 64 * 4 * 2) return;  // fail loudly

    // --- graph preprocessing (2 dispatches, no memset) ---
    partition_det<<<nchunk, 256, 0, stream>>>(src, dst, pcnt, ebuf, E, nbkt, nchunk);
    csr_build_flat<<<nbkt, 512, 0, stream>>>(ebuf, pcnt, offs, dinv, csr, N, E, nbkt, nchunk);

    // --- layer 1 ---
    gemm_mfma<128, false><<<(N + 63) / 64, 256, 0, stream>>>(
        x, W1, dinv, (unsigned short*)g1b, N);
    agg1_kernel<<<(N + 3) / 4, 256, 0, stream>>>(g1b, offs, csr, dinv, b1, a1b, N);

    // --- layer 2 ---
    gemm_mfma<64, true><<<(N + 63) / 64, 256, 0, stream>>>(
        a1b, W2, dinv, (unsigned short*)g2b, N);
    agg2_kernel<<<(N + 7) / 8, 256, 0, stream>>>(g2b, offs, csr, dinv, b2, out, N);
}

// Round 12
// 204.587 us; speedup vs baseline: 1.3345x; 1.3345x over previous
//
#include <hip/hip_runtime.h>
#include <hip/hip_bf16.h>

// ---------------------------------------------------------------------------
// 2-layer GCN. g[j] = dinv[j]*(X@W)[j] stored BF16; out[i] = dinv[i]*(g[i]+sum g[j]) + b
// CSR-by-destination built once, reused by both layers.
// R2-R8: bucketed CSR build, bf16 tables, MFMA GEMMs, deep gather unroll,
//        fixed-capacity buckets.
// R9-R11 FAILED: coop fusion / per-chunk slots — both starved csr_build.
// R12: exact R8 structure; csr_build at 1024 threads (16 waves) for latency
//      hiding on the per-bucket edge stream.
// ---------------------------------------------------------------------------

typedef short bf16x8 __attribute__((ext_vector_type(8)));
typedef float f32x4 __attribute__((ext_vector_type(4)));

__device__ __forceinline__ unsigned pack_bf16_2(float a, float b) {
    unsigned ua = __builtin_bit_cast(unsigned, a);
    unsigned ub = __builtin_bit_cast(unsigned, b);
    ua += 0x7FFFu + ((ua >> 16) & 1u);   // RNE to bf16
    ub += 0x7FFFu + ((ub >> 16) & 1u);
    return (ua >> 16) | (ub & 0xFFFF0000u);
}
__device__ __forceinline__ unsigned short bf16_1(float a) {
    unsigned ua = __builtin_bit_cast(unsigned, a);
    ua += 0x7FFFu + ((ua >> 16) & 1u);
    return (unsigned short)(ua >> 16);
}
__device__ __forceinline__ float bf16_lo(unsigned v) {
    return __builtin_bit_cast(float, v << 16);
}
__device__ __forceinline__ float bf16_hi(unsigned v) {
    return __builtin_bit_cast(float, v & 0xFFFF0000u);
}

// partition edges into fixed-capacity dst-buckets (bucket b = dst>>10 at
// ebuf[b*cap ...]). bcur[b] is a global running count (L2-hot, 98 ints).
__global__ __launch_bounds__(256) void partition_fixed(const int* __restrict__ src,
                                                       const int* __restrict__ dst,
                                                       int* __restrict__ bcur,
                                                       int2* __restrict__ ebuf,
                                                       int E, int nb, int cap) {
    __shared__ int hist[256];
    __shared__ int basel[256];
    const int tid = threadIdx.x;
    const int c0 = blockIdx.x * 4096;
    for (int t = tid; t < nb; t += 256) hist[t] = 0;
    __syncthreads();
    int s[16], d[16], r[16];
#pragma unroll
    for (int i = 0; i < 16; ++i) {
        int idx = c0 + i * 256 + tid;
        if (idx < E) {
            s[i] = src[idx];
            d[i] = dst[idx];
            r[i] = atomicAdd(&hist[d[i] >> 10], 1);
        } else {
            d[i] = -1;
        }
    }
    __syncthreads();
    for (int t = tid; t < nb; t += 256) basel[t] = hist[t] ? atomicAdd(&bcur[t], hist[t]) : 0;
    __syncthreads();
#pragma unroll
    for (int i = 0; i < 16; ++i) {
        if (d[i] >= 0) {
            int b = d[i] >> 10;
            int pos = basel[b] + r[i];
            if (pos < cap)   // overflow guard (loud failure via absmax)
                ebuf[(size_t)b * cap + pos] = make_int2(s[i], d[i]);
        }
    }
}

// R12: one 1024-thread block (16 waves) per dst-bucket.
// pass A: LDS degree hist -> 1024-wide scan -> offs, dinv;
// pass B: LDS cursors -> compact csr placement. Heavy atomics in LDS.
__global__ __launch_bounds__(1024) void csr_build(const int2* __restrict__ ebuf,
                                                  const int* __restrict__ bcur,
                                                  int* __restrict__ offs,
                                                  float* __restrict__ dinv,
                                                  int* __restrict__ csr,
                                                  int N, int E, int nb, int cap) {
    __shared__ int hist[1024];
    __shared__ int lofs[1024];
    __shared__ int stmp[1024];
    __shared__ int s_e0, s_cnt;
    const int b = blockIdx.x;
    const int tid = threadIdx.x;
    const int n0 = b << 10;

    // exclusive base of this bucket in the compact csr = scan of bcur counts
    // (256-wide scan over nb <= 256 buckets, first 256 threads)
    {
        int bc = 0;
        if (tid < 256) {
            bc = (tid < nb) ? bcur[tid] : 0;
            stmp[tid] = bc;
        }
        __syncthreads();
        int run = (tid < 256) ? stmp[tid] : 0;
        for (int off = 1; off < 256; off <<= 1) {
            int t = (tid >= off && tid < 256) ? stmp[tid - off] : 0;
            __syncthreads();
            if (tid < 256) { run += t; stmp[tid] = run; }
            __syncthreads();
        }
        if (tid == b) { s_cnt = bc; s_e0 = run - bc; }
        __syncthreads();
    }
    const int e0 = s_e0;
    const int cnt = s_cnt;
    const int2* eb = ebuf + (size_t)b * cap;

    // pass A: degree histogram (contiguous coalesced stream, 16 waves)
    hist[tid] = 0;
    __syncthreads();
    for (int e = tid; e < cnt; e += 1024)
        atomicAdd(&hist[eb[e].y & 1023], 1);
    __syncthreads();
    // 1024-wide exclusive scan of degrees (1 node/thread)
    const int v = hist[tid];
    stmp[tid] = v;
    __syncthreads();
    int run = v;
    for (int off = 1; off < 1024; off <<= 1) {
        int t = (tid >= off) ? stmp[tid - off] : 0;
        __syncthreads();
        run += t;
        stmp[tid] = run;
        __syncthreads();
    }
    const int excl = run - v;
    lofs[tid] = excl;
    {
        int node = n0 + tid;
        if (node < N) {
            offs[node] = e0 + excl;
            dinv[node] = rsqrtf((float)(v + 1));   // +1 self-loop
        }
    }
    __syncthreads();
    // pass B: place edges via LDS cursors (lofs consumed in place)
    for (int e = tid; e < cnt; e += 1024) {
        int2 p = eb[e];
        int pos = atomicAdd(&lofs[p.y & 1023], 1);
        csr[e0 + pos] = p.x;
    }
    if (b == 0 && tid == 0) offs[N] = E;
}

// MFMA GEMM. Gs[r*COUT+c] = bf16( dinv[r] * sum_k X[r,k]*W[k,c] ). K=128.
template <int COUT, bool INBF16>
__global__ __launch_bounds__(256) void gemm_mfma(const void* __restrict__ Xv,
                                                 const float* __restrict__ W,
                                                 const float* __restrict__ dinv,
                                                 unsigned short* __restrict__ Gs, int N) {
    constexpr int BR = 64;
    constexpr int CPT = COUT / 16;
    __shared__ unsigned short sx[BR][136];
    __shared__ unsigned short swT[COUT][136];
    const int tid = threadIdx.x;
    const int r0 = blockIdx.x * BR;

    if constexpr (INBF16) {
        const unsigned* Xb = (const unsigned*)Xv;
#pragma unroll
        for (int q = 0; q < 4; ++q) {
            int off = q * 1024 + tid * 4;
            int row = off >> 6;
            int ku = off & 63;
            size_t grow = (size_t)min(r0 + row, N - 1);
            uint4 v = *reinterpret_cast<const uint4*>(&Xb[grow * 64 + ku]);
            *reinterpret_cast<uint4*>(&sx[row][ku * 2]) = v;
        }
    } else {
        const float* Xf = (const float*)Xv;
#pragma unroll
        for (int q = 0; q < 8; ++q) {
            int off = q * 1024 + tid * 4;
            int row = off >> 7;
            int k = off & 127;
            size_t grow = (size_t)min(r0 + row, N - 1);
            float4 v = *reinterpret_cast<const float4*>(&Xf[grow * 128 + k]);
            uint2 pk;
            pk.x = pack_bf16_2(v.x, v.y);
            pk.y = pack_bf16_2(v.z, v.w);
            *reinterpret_cast<uint2*>(&sx[row][k]) = pk;
        }
    }
#pragma unroll
    for (int q = 0; q < COUT / 8; ++q) {
        int off = q * 1024 + tid * 4;
        int k = off / COUT;
        int c = off % COUT;
        float4 v = *reinterpret_cast<const float4*>(&W[off]);
        swT[c + 0][k] = bf16_1(v.x);
        swT[c + 1][k] = bf16_1(v.y);
        swT[c + 2][k] = bf16_1(v.z);
        swT[c + 3][k] = bf16_1(v.w);
    }
    __syncthreads();

    const int w = tid >> 6;
    const int l = tid & 63;
    const int lr = l & 15;
    const int lkg = l >> 4;
    f32x4 acc[CPT];
#pragma unroll
    for (int c = 0; c < CPT; ++c) acc[c] = f32x4{0.f, 0.f, 0.f, 0.f};

#pragma unroll
    for (int ks = 0; ks < 4; ++ks) {
        const int k0 = ks * 32 + lkg * 8;
        bf16x8 a = *reinterpret_cast<const bf16x8*>(&sx[w * 16 + lr][k0]);
#pragma unroll
        for (int c = 0; c < CPT; ++c) {
            bf16x8 b = *reinterpret_cast<const bf16x8*>(&swT[c * 16 + lr][k0]);
            acc[c] = __builtin_amdgcn_mfma_f32_16x16x32_bf16(a, b, acc[c], 0, 0, 0);
        }
    }

#pragma unroll
    for (int r = 0; r < 4; ++r) {
        int gr = r0 + w * 16 + lkg * 4 + r;
        if (gr < N) {
            float di = dinv[gr];
#pragma unroll
            for (int c = 0; c < CPT; ++c)
                Gs[(size_t)gr * COUT + c * 16 + lr] = bf16_1(acc[c][r] * di);
        }
    }
}

// Layer-1 aggregate: 128 bf16 cols/row, one wave per node, 16-deep gather ladder.
__global__ __launch_bounds__(256) void agg1_kernel(const unsigned* __restrict__ Gb,
                                                   const int* __restrict__ offs,
                                                   const int* __restrict__ csr,
                                                   const float* __restrict__ dinv,
                                                   const float* __restrict__ bias,
                                                   unsigned* __restrict__ outb, int N) {
    int node = (blockIdx.x * blockDim.x + threadIdx.x) >> 6;
    int lane = threadIdx.x & 63;
    if (node >= N) return;
    int e = offs[node];
    const int end = offs[node + 1];
    unsigned sv = Gb[(size_t)node * 64 + lane];
    float ax = bf16_lo(sv), ay = bf16_hi(sv);
    for (; e + 16 <= end; e += 16) {
        int j[16];
#pragma unroll
        for (int q = 0; q < 16; ++q) j[q] = csr[e + q];
        unsigned v[16];
#pragma unroll
        for (int q = 0; q < 16; ++q) v[q] = Gb[(size_t)j[q] * 64 + lane];
#pragma unroll
        for (int q = 0; q < 16; ++q) { ax += bf16_lo(v[q]); ay += bf16_hi(v[q]); }
    }
    for (; e + 8 <= end; e += 8) {
        int j[8];
#pragma unroll
        for (int q = 0; q < 8; ++q) j[q] = csr[e + q];
        unsigned v[8];
#pragma unroll
        for (int q = 0; q < 8; ++q) v[q] = Gb[(size_t)j[q] * 64 + lane];
#pragma unroll
        for (int q = 0; q < 8; ++q) { ax += bf16_lo(v[q]); ay += bf16_hi(v[q]); }
    }
    for (; e + 4 <= end; e += 4) {
        int j0 = csr[e], j1 = csr[e + 1], j2 = csr[e + 2], j3 = csr[e + 3];
        unsigned v0 = Gb[(size_t)j0 * 64 + lane];
        unsigned v1 = Gb[(size_t)j1 * 64 + lane];
        unsigned v2 = Gb[(size_t)j2 * 64 + lane];
        unsigned v3 = Gb[(size_t)j3 * 64 + lane];
        ax += bf16_lo(v0) + bf16_lo(v1) + bf16_lo(v2) + bf16_lo(v3);
        ay += bf16_hi(v0) + bf16_hi(v1) + bf16_hi(v2) + bf16_hi(v3);
    }
    for (; e < end; ++e) {
        unsigned v = Gb[(size_t)csr[e] * 64 + lane];
        ax += bf16_lo(v); ay += bf16_hi(v);
    }
    float di = dinv[node];
    float ox = fmaxf(ax * di + bias[lane * 2 + 0], 0.f);
    float oy = fmaxf(ay * di + bias[lane * 2 + 1], 0.f);
    outb[(size_t)node * 64 + lane] = pack_bf16_2(ox, oy);
}

// Layer-2 aggregate: 64 bf16 cols/row = 32 uints; two nodes per wave; 16-deep ladder.
__global__ __launch_bounds__(256) void agg2_kernel(const unsigned* __restrict__ Gb,
                                                   const int* __restrict__ offs,
                                                   const int* __restrict__ csr,
                                                   const float* __restrict__ dinv,
                                                   const float* __restrict__ bias,
                                                   float* __restrict__ out, int N) {
    int tid = blockIdx.x * blockDim.x + threadIdx.x;
    int node = (tid >> 6) * 2 + ((threadIdx.x >> 5) & 1);
    int c = threadIdx.x & 31;
    if (node >= N) return;
    int e = offs[node];
    const int end = offs[node + 1];
    unsigned sv = Gb[(size_t)node * 32 + c];
    float ax = bf16_lo(sv), ay = bf16_hi(sv);
    for (; e + 16 <= end; e += 16) {
        int j[16];
#pragma unroll
        for (int q = 0; q < 16; ++q) j[q] = csr[e + q];
        unsigned v[16];
#pragma unroll
        for (int q = 0; q < 16; ++q) v[q] = Gb[(size_t)j[q] * 32 + c];
#pragma unroll
        for (int q = 0; q < 16; ++q) { ax += bf16_lo(v[q]); ay += bf16_hi(v[q]); }
    }
    for (; e + 8 <= end; e += 8) {
        int j[8];
#pragma unroll
        for (int q = 0; q < 8; ++q) j[q] = csr[e + q];
        unsigned v[8];
#pragma unroll
        for (int q = 0; q < 8; ++q) v[q] = Gb[(size_t)j[q] * 32 + c];
#pragma unroll
        for (int q = 0; q < 8; ++q) { ax += bf16_lo(v[q]); ay += bf16_hi(v[q]); }
    }
    for (; e + 4 <= end; e += 4) {
        int j0 = csr[e], j1 = csr[e + 1], j2 = csr[e + 2], j3 = csr[e + 3];
        unsigned v0 = Gb[(size_t)j0 * 32 + c];
        unsigned v1 = Gb[(size_t)j1 * 32 + c];
        unsigned v2 = Gb[(size_t)j2 * 32 + c];
        unsigned v3 = Gb[(size_t)j3 * 32 + c];
        ax += bf16_lo(v0) + bf16_lo(v1) + bf16_lo(v2) + bf16_lo(v3);
        ay += bf16_hi(v0) + bf16_hi(v1) + bf16_hi(v2) + bf16_hi(v3);
    }
    for (; e < end; ++e) {
        unsigned v = Gb[(size_t)csr[e] * 32 + c];
        ax += bf16_lo(v); ay += bf16_hi(v);
    }
    float di = dinv[node];
    float2 o;
    o.x = ax * di + bias[c * 2 + 0];
    o.y = ay * di + bias[c * 2 + 1];
    *reinterpret_cast<float2*>(&out[(size_t)node * 64 + c * 2]) = o;
}

extern "C" void kernel_launch(void* const* d_in, const int* in_sizes, int n_in,
                              void* d_out, int out_size, void* d_ws, size_t ws_size,
                              hipStream_t stream) {
    const float* x  = (const float*)d_in[0];
    const int*   ei = (const int*)d_in[1];
    const float* W1 = (const float*)d_in[2];
    const float* b1 = (const float*)d_in[3];
    const float* W2 = (const float*)d_in[4];
    const float* b2 = (const float*)d_in[5];
    float* out = (float*)d_out;

    const int N = in_sizes[0] / 128;
    const int E = in_sizes[1] / 2;
    const int* src = ei;
    const int* dst = ei + E;
    const int nbkt = (N + 1023) >> 10;                // must be <= 256
    const int cap = E / nbkt + E / (4 * nbkt) + 1024; // ~37 sigma headroom, uniform dst

    // Workspace layout
    unsigned* g1b = (unsigned*)d_ws;                 // N*64 uints (25.6MB); reused as g2b
    unsigned* a1b = g1b + (size_t)N * 64;            // N*64 uints bf16 a1
    unsigned* g2b = g1b;
    int2* ebuf = (int2*)d_ws;                        // nbkt*cap*8B, aliases g1b (lifetime-disjoint)
    char* p = (char*)(a1b + (size_t)N * 64);
    float* dinv = (float*)p; p += (((size_t)N * 4) + 15) & ~(size_t)15;
    int* offs = (int*)p;   p += (((size_t)(N + 1) * 4) + 15) & ~(size_t)15;
    int* csr = (int*)p;    p += (((size_t)E * 4) + 15) & ~(size_t)15;
    int* bcur = (int*)p;   p += (((size_t)256 * 4) + 15) & ~(size_t)15;
    if ((size_t)(p - (char*)d_ws) > ws_size || nbkt > 256 ||
        (size_t)nbkt * cap * 8 > (size_t)N * 64 * 4 * 2) return;  // fail loudly

    // --- graph preprocessing (3 dispatches) ---
    hipMemsetAsync(bcur, 0, 256 * sizeof(int), stream);
    partition_fixed<<<(E + 4095) / 4096, 256, 0, stream>>>(src, dst, bcur, ebuf, E, nbkt, cap);
    csr_build<<<nbkt, 1024, 0, stream>>>(ebuf, bcur, offs, dinv, csr, N, E, nbkt, cap);

    // --- layer 1 ---
    gemm_mfma<128, false><<<(N + 63) / 64, 256, 0, stream>>>(
        x, W1, dinv, (unsigned short*)g1b, N);
    agg1_kernel<<<(N + 3) / 4, 256, 0, stream>>>(g1b, offs, csr, dinv, b1, a1b, N);

    // --- layer 2 ---
    gemm_mfma<64, true><<<(N + 63) / 64, 256, 0, stream>>>(
        a1b, W2, dinv, (unsigned short*)g2b, N);
    agg2_kernel<<<(N + 7) / 8, 256, 0, stream>>>(g2b, offs, csr, dinv, b2, out, N);
}

// Round 13
// 202.088 us; speedup vs baseline: 1.3510x; 1.0124x over previous
//
#include <hip/hip_runtime.h>
#include <hip/hip_bf16.h>

// ---------------------------------------------------------------------------
// 2-layer GCN. g[j] = dinv[j]*(X@W)[j] stored BF16; out[i] = dinv[i]*(g[i]+sum g[j]) + b
// CSR-by-destination built once, reused by both layers.
// R2-R8: bucketed CSR build, bf16 tables, MFMA GEMMs, deep gather unroll,
//        fixed-capacity buckets.
// R9-R11 FAILED: coop fusion / per-chunk slots — both starved csr_build.
// R12: csr_build at 1024 threads (16 waves) — 204.6us.
// R13: ebuf packed to 4B/edge (src | (dst&1023)<<17; bucket id implicit in
//      slot address) — halves partition write + csr_build stream reads.
// ---------------------------------------------------------------------------

typedef short bf16x8 __attribute__((ext_vector_type(8)));
typedef float f32x4 __attribute__((ext_vector_type(4)));

__device__ __forceinline__ unsigned pack_bf16_2(float a, float b) {
    unsigned ua = __builtin_bit_cast(unsigned, a);
    unsigned ub = __builtin_bit_cast(unsigned, b);
    ua += 0x7FFFu + ((ua >> 16) & 1u);   // RNE to bf16
    ub += 0x7FFFu + ((ub >> 16) & 1u);
    return (ua >> 16) | (ub & 0xFFFF0000u);
}
__device__ __forceinline__ unsigned short bf16_1(float a) {
    unsigned ua = __builtin_bit_cast(unsigned, a);
    ua += 0x7FFFu + ((ua >> 16) & 1u);
    return (unsigned short)(ua >> 16);
}
__device__ __forceinline__ float bf16_lo(unsigned v) {
    return __builtin_bit_cast(float, v << 16);
}
__device__ __forceinline__ float bf16_hi(unsigned v) {
    return __builtin_bit_cast(float, v & 0xFFFF0000u);
}

// partition edges into fixed-capacity dst-buckets; entry = src | (dst&1023)<<17.
// bcur[b] is a global running count (L2-hot, <=256 ints).
__global__ __launch_bounds__(256) void partition_fixed(const int* __restrict__ src,
                                                       const int* __restrict__ dst,
                                                       int* __restrict__ bcur,
                                                       unsigned* __restrict__ ebuf,
                                                       int E, int nb, int cap) {
    __shared__ int hist[256];
    __shared__ int basel[256];
    const int tid = threadIdx.x;
    const int c0 = blockIdx.x * 4096;
    for (int t = tid; t < nb; t += 256) hist[t] = 0;
    __syncthreads();
    int s[16], d[16], r[16];
#pragma unroll
    for (int i = 0; i < 16; ++i) {
        int idx = c0 + i * 256 + tid;
        if (idx < E) {
            s[i] = src[idx];
            d[i] = dst[idx];
            r[i] = atomicAdd(&hist[d[i] >> 10], 1);
        } else {
            d[i] = -1;
        }
    }
    __syncthreads();
    for (int t = tid; t < nb; t += 256) basel[t] = hist[t] ? atomicAdd(&bcur[t], hist[t]) : 0;
    __syncthreads();
#pragma unroll
    for (int i = 0; i < 16; ++i) {
        if (d[i] >= 0) {
            int b = d[i] >> 10;
            int pos = basel[b] + r[i];
            if (pos < cap)   // overflow guard (loud failure via absmax)
                ebuf[(size_t)b * cap + pos] =
                    (unsigned)s[i] | ((unsigned)(d[i] & 1023) << 17);
        }
    }
}

// one 1024-thread block (16 waves) per dst-bucket.
// pass A: LDS degree hist -> 1024-wide scan -> offs, dinv;
// pass B: LDS cursors -> compact csr placement. Heavy atomics in LDS.
__global__ __launch_bounds__(1024) void csr_build(const unsigned* __restrict__ ebuf,
                                                  const int* __restrict__ bcur,
                                                  int* __restrict__ offs,
                                                  float* __restrict__ dinv,
                                                  int* __restrict__ csr,
                                                  int N, int E, int nb, int cap) {
    __shared__ int hist[1024];
    __shared__ int lofs[1024];
    __shared__ int stmp[1024];
    __shared__ int s_e0, s_cnt;
    const int b = blockIdx.x;
    const int tid = threadIdx.x;
    const int n0 = b << 10;

    // exclusive base of this bucket in the compact csr = scan of bcur counts
    {
        int bc = 0;
        if (tid < 256) {
            bc = (tid < nb) ? bcur[tid] : 0;
            stmp[tid] = bc;
        }
        __syncthreads();
        int run = (tid < 256) ? stmp[tid] : 0;
        for (int off = 1; off < 256; off <<= 1) {
            int t = (tid >= off && tid < 256) ? stmp[tid - off] : 0;
            __syncthreads();
            if (tid < 256) { run += t; stmp[tid] = run; }
            __syncthreads();
        }
        if (tid == b) { s_cnt = bc; s_e0 = run - bc; }
        __syncthreads();
    }
    const int e0 = s_e0;
    const int cnt = s_cnt;
    const unsigned* eb = ebuf + (size_t)b * cap;

    // pass A: degree histogram (contiguous coalesced stream, 16 waves)
    hist[tid] = 0;
    __syncthreads();
    for (int e = tid; e < cnt; e += 1024)
        atomicAdd(&hist[(eb[e] >> 17) & 1023], 1);
    __syncthreads();
    // 1024-wide exclusive scan of degrees (1 node/thread)
    const int v = hist[tid];
    stmp[tid] = v;
    __syncthreads();
    int run = v;
    for (int off = 1; off < 1024; off <<= 1) {
        int t = (tid >= off) ? stmp[tid - off] : 0;
        __syncthreads();
        run += t;
        stmp[tid] = run;
        __syncthreads();
    }
    const int excl = run - v;
    lofs[tid] = excl;
    {
        int node = n0 + tid;
        if (node < N) {
            offs[node] = e0 + excl;
            dinv[node] = rsqrtf((float)(v + 1));   // +1 self-loop
        }
    }
    __syncthreads();
    // pass B: place edges via LDS cursors (lofs consumed in place)
    for (int e = tid; e < cnt; e += 1024) {
        unsigned w = eb[e];
        int pos = atomicAdd(&lofs[(w >> 17) & 1023], 1);
        csr[e0 + pos] = (int)(w & 0x1FFFFu);
    }
    if (b == 0 && tid == 0) offs[N] = E;
}

// MFMA GEMM. Gs[r*COUT+c] = bf16( dinv[r] * sum_k X[r,k]*W[k,c] ). K=128.
template <int COUT, bool INBF16>
__global__ __launch_bounds__(256) void gemm_mfma(const void* __restrict__ Xv,
                                                 const float* __restrict__ W,
                                                 const float* __restrict__ dinv,
                                                 unsigned short* __restrict__ Gs, int N) {
    constexpr int BR = 64;
    constexpr int CPT = COUT / 16;
    __shared__ unsigned short sx[BR][136];
    __shared__ unsigned short swT[COUT][136];
    const int tid = threadIdx.x;
    const int r0 = blockIdx.x * BR;

    if constexpr (INBF16) {
        const unsigned* Xb = (const unsigned*)Xv;
#pragma unroll
        for (int q = 0; q < 4; ++q) {
            int off = q * 1024 + tid * 4;
            int row = off >> 6;
            int ku = off & 63;
            size_t grow = (size_t)min(r0 + row, N - 1);
            uint4 v = *reinterpret_cast<const uint4*>(&Xb[grow * 64 + ku]);
            *reinterpret_cast<uint4*>(&sx[row][ku * 2]) = v;
        }
    } else {
        const float* Xf = (const float*)Xv;
#pragma unroll
        for (int q = 0; q < 8; ++q) {
            int off = q * 1024 + tid * 4;
            int row = off >> 7;
            int k = off & 127;
            size_t grow = (size_t)min(r0 + row, N - 1);
            float4 v = *reinterpret_cast<const float4*>(&Xf[grow * 128 + k]);
            uint2 pk;
            pk.x = pack_bf16_2(v.x, v.y);
            pk.y = pack_bf16_2(v.z, v.w);
            *reinterpret_cast<uint2*>(&sx[row][k]) = pk;
        }
    }
#pragma unroll
    for (int q = 0; q < COUT / 8; ++q) {
        int off = q * 1024 + tid * 4;
        int k = off / COUT;
        int c = off % COUT;
        float4 v = *reinterpret_cast<const float4*>(&W[off]);
        swT[c + 0][k] = bf16_1(v.x);
        swT[c + 1][k] = bf16_1(v.y);
        swT[c + 2][k] = bf16_1(v.z);
        swT[c + 3][k] = bf16_1(v.w);
    }
    __syncthreads();

    const int w = tid >> 6;
    const int l = tid & 63;
    const int lr = l & 15;
    const int lkg = l >> 4;
    f32x4 acc[CPT];
#pragma unroll
    for (int c = 0; c < CPT; ++c) acc[c] = f32x4{0.f, 0.f, 0.f, 0.f};

#pragma unroll
    for (int ks = 0; ks < 4; ++ks) {
        const int k0 = ks * 32 + lkg * 8;
        bf16x8 a = *reinterpret_cast<const bf16x8*>(&sx[w * 16 + lr][k0]);
#pragma unroll
        for (int c = 0; c < CPT; ++c) {
            bf16x8 b = *reinterpret_cast<const bf16x8*>(&swT[c * 16 + lr][k0]);
            acc[c] = __builtin_amdgcn_mfma_f32_16x16x32_bf16(a, b, acc[c], 0, 0, 0);
        }
    }

#pragma unroll
    for (int r = 0; r < 4; ++r) {
        int gr = r0 + w * 16 + lkg * 4 + r;
        if (gr < N) {
            float di = dinv[gr];
#pragma unroll
            for (int c = 0; c < CPT; ++c)
                Gs[(size_t)gr * COUT + c * 16 + lr] = bf16_1(acc[c][r] * di);
        }
    }
}

// Layer-1 aggregate: 128 bf16 cols/row, one wave per node, 16-deep gather ladder.
__global__ __launch_bounds__(256) void agg1_kernel(const unsigned* __restrict__ Gb,
                                                   const int* __restrict__ offs,
                                                   const int* __restrict__ csr,
                                                   const float* __restrict__ dinv,
                                                   const float* __restrict__ bias,
                                                   unsigned* __restrict__ outb, int N) {
    int node = (blockIdx.x * blockDim.x + threadIdx.x) >> 6;
    int lane = threadIdx.x & 63;
    if (node >= N) return;
    int e = offs[node];
    const int end = offs[node + 1];
    unsigned sv = Gb[(size_t)node * 64 + lane];
    float ax = bf16_lo(sv), ay = bf16_hi(sv);
    for (; e + 16 <= end; e += 16) {
        int j[16];
#pragma unroll
        for (int q = 0; q < 16; ++q) j[q] = csr[e + q];
        unsigned v[16];
#pragma unroll
        for (int q = 0; q < 16; ++q) v[q] = Gb[(size_t)j[q] * 64 + lane];
#pragma unroll
        for (int q = 0; q < 16; ++q) { ax += bf16_lo(v[q]); ay += bf16_hi(v[q]); }
    }
    for (; e + 8 <= end; e += 8) {
        int j[8];
#pragma unroll
        for (int q = 0; q < 8; ++q) j[q] = csr[e + q];
        unsigned v[8];
#pragma unroll
        for (int q = 0; q < 8; ++q) v[q] = Gb[(size_t)j[q] * 64 + lane];
#pragma unroll
        for (int q = 0; q < 8; ++q) { ax += bf16_lo(v[q]); ay += bf16_hi(v[q]); }
    }
    for (; e + 4 <= end; e += 4) {
        int j0 = csr[e], j1 = csr[e + 1], j2 = csr[e + 2], j3 = csr[e + 3];
        unsigned v0 = Gb[(size_t)j0 * 64 + lane];
        unsigned v1 = Gb[(size_t)j1 * 64 + lane];
        unsigned v2 = Gb[(size_t)j2 * 64 + lane];
        unsigned v3 = Gb[(size_t)j3 * 64 + lane];
        ax += bf16_lo(v0) + bf16_lo(v1) + bf16_lo(v2) + bf16_lo(v3);
        ay += bf16_hi(v0) + bf16_hi(v1) + bf16_hi(v2) + bf16_hi(v3);
    }
    for (; e < end; ++e) {
        unsigned v = Gb[(size_t)csr[e] * 64 + lane];
        ax += bf16_lo(v); ay += bf16_hi(v);
    }
    float di = dinv[node];
    float ox = fmaxf(ax * di + bias[lane * 2 + 0], 0.f);
    float oy = fmaxf(ay * di + bias[lane * 2 + 1], 0.f);
    outb[(size_t)node * 64 + lane] = pack_bf16_2(ox, oy);
}

// Layer-2 aggregate: 64 bf16 cols/row = 32 uints; two nodes per wave; 16-deep ladder.
__global__ __launch_bounds__(256) void agg2_kernel(const unsigned* __restrict__ Gb,
                                                   const int* __restrict__ offs,
                                                   const int* __restrict__ csr,
                                                   const float* __restrict__ dinv,
                                                   const float* __restrict__ bias,
                                                   float* __restrict__ out, int N) {
    int tid = blockIdx.x * blockDim.x + threadIdx.x;
    int node = (tid >> 6) * 2 + ((threadIdx.x >> 5) & 1);
    int c = threadIdx.x & 31;
    if (node >= N) return;
    int e = offs[node];
    const int end = offs[node + 1];
    unsigned sv = Gb[(size_t)node * 32 + c];
    float ax = bf16_lo(sv), ay = bf16_hi(sv);
    for (; e + 16 <= end; e += 16) {
        int j[16];
#pragma unroll
        for (int q = 0; q < 16; ++q) j[q] = csr[e + q];
        unsigned v[16];
#pragma unroll
        for (int q = 0; q < 16; ++q) v[q] = Gb[(size_t)j[q] * 32 + c];
#pragma unroll
        for (int q = 0; q < 16; ++q) { ax += bf16_lo(v[q]); ay += bf16_hi(v[q]); }
    }
    for (; e + 8 <= end; e += 8) {
        int j[8];
#pragma unroll
        for (int q = 0; q < 8; ++q) j[q] = csr[e + q];
        unsigned v[8];
#pragma unroll
        for (int q = 0; q < 8; ++q) v[q] = Gb[(size_t)j[q] * 32 + c];
#pragma unroll
        for (int q = 0; q < 8; ++q) { ax += bf16_lo(v[q]); ay += bf16_hi(v[q]); }
    }
    for (; e + 4 <= end; e += 4) {
        int j0 = csr[e], j1 = csr[e + 1], j2 = csr[e + 2], j3 = csr[e + 3];
        unsigned v0 = Gb[(size_t)j0 * 32 + c];
        unsigned v1 = Gb[(size_t)j1 * 32 + c];
        unsigned v2 = Gb[(size_t)j2 * 32 + c];
        unsigned v3 = Gb[(size_t)j3 * 32 + c];
        ax += bf16_lo(v0) + bf16_lo(v1) + bf16_lo(v2) + bf16_lo(v3);
        ay += bf16_hi(v0) + bf16_hi(v1) + bf16_hi(v2) + bf16_hi(v3);
    }
    for (; e < end; ++e) {
        unsigned v = Gb[(size_t)csr[e] * 32 + c];
        ax += bf16_lo(v); ay += bf16_hi(v);
    }
    float di = dinv[node];
    float2 o;
    o.x = ax * di + bias[c * 2 + 0];
    o.y = ay * di + bias[c * 2 + 1];
    *reinterpret_cast<float2*>(&out[(size_t)node * 64 + c * 2]) = o;
}

extern "C" void kernel_launch(void* const* d_in, const int* in_sizes, int n_in,
                              void* d_out, int out_size, void* d_ws, size_t ws_size,
                              hipStream_t stream) {
    const float* x  = (const float*)d_in[0];
    const int*   ei = (const int*)d_in[1];
    const float* W1 = (const float*)d_in[2];
    const float* b1 = (const float*)d_in[3];
    const float* W2 = (const float*)d_in[4];
    const float* b2 = (const float*)d_in[5];
    float* out = (float*)d_out;

    const int N = in_sizes[0] / 128;
    const int E = in_sizes[1] / 2;
    const int* src = ei;
    const int* dst = ei + E;
    const int nbkt = (N + 1023) >> 10;                // must be <= 256
    const int cap = E / nbkt + E / (4 * nbkt) + 1024; // ~37 sigma headroom, uniform dst

    // Workspace layout
    unsigned* g1b = (unsigned*)d_ws;                 // N*64 uints (25.6MB); reused as g2b
    unsigned* a1b = g1b + (size_t)N * 64;            // N*64 uints bf16 a1
    unsigned* g2b = g1b;
    unsigned* ebuf = (unsigned*)d_ws;                // nbkt*cap*4B, aliases g1b (lifetime-disjoint)
    char* p = (char*)(a1b + (size_t)N * 64);
    float* dinv = (float*)p; p += (((size_t)N * 4) + 15) & ~(size_t)15;
    int* offs = (int*)p;   p += (((size_t)(N + 1) * 4) + 15) & ~(size_t)15;
    int* csr = (int*)p;    p += (((size_t)E * 4) + 15) & ~(size_t)15;
    int* bcur = (int*)p;   p += (((size_t)256 * 4) + 15) & ~(size_t)15;
    if ((size_t)(p - (char*)d_ws) > ws_size || nbkt > 256 || N > (1 << 17) ||
        (size_t)nbkt * cap * 4 > (size_t)N * 64 * 4) return;  // fail loudly

    // --- graph preprocessing (3 dispatches) ---
    hipMemsetAsync(bcur, 0, 256 * sizeof(int), stream);
    partition_fixed<<<(E + 4095) / 4096, 256, 0, stream>>>(src, dst, bcur, ebuf, E, nbkt, cap);
    csr_build<<<nbkt, 1024, 0, stream>>>(ebuf, bcur, offs, dinv, csr, N, E, nbkt, cap);

    // --- layer 1 ---
    gemm_mfma<128, false><<<(N + 63) / 64, 256, 0, stream>>>(
        x, W1, dinv, (unsigned short*)g1b, N);
    agg1_kernel<<<(N + 3) / 4, 256, 0, stream>>>(g1b, offs, csr, dinv, b1, a1b, N);

    // --- layer 2 ---
    gemm_mfma<64, true><<<(N + 63) / 64, 256, 0, stream>>>(
        a1b, W2, dinv, (unsigned short*)g2b, N);
    agg2_kernel<<<(N + 7) / 8, 256, 0, stream>>>(g2b, offs, csr, dinv, b2, out, N);
}